// Round 3
// baseline (586.484 us; speedup 1.0000x reference)
//
#include <hip/hip_runtime.h>
#include <stdint.h>

// Problem constants (fixed by the reference)
#define CC   21        // n_classes
#define HWp  262144    // H*W = 512*512
#define NPIX 2097152   // B*H*W = 8*512*512
#define PXT  4         // pixels per thread (4 consecutive hw; HW % 4 == 0)
#define CMS  24        // padded LDS row stride for transposed CM (16B aligned)

// post_i = p_i * (CM . c)_i / sum_i p_i * (CM . c)_i
// (row-normalizations of p and c cancel in the final normalization)
__global__ __launch_bounds__(256, 3)
void ep_kernel(const float* __restrict__ prior,
               const float* __restrict__ current,
               const float* __restrict__ cm,
               float* __restrict__ out)
{
    // cmT[j*CMS + i] = CM[i][j]; pad i=21..23 with 0 so rows are b128-friendly
    __shared__ __align__(16) float cmT[CC * CMS];
    const int tid = threadIdx.x;
    for (int k = tid; k < CC * CMS; k += 256) {
        int j = k / CMS, i = k - j * CMS;
        cmT[k] = (i < CC) ? cm[i * CC + j] : 0.f;
    }
    __syncthreads();

    const int n0   = (blockIdx.x * 256 + tid) * PXT;   // base pixel index
    const int b    = n0 / HWp;
    const int hw   = n0 - b * HWp;
    const int base = b * CC * HWp + hw;                // + c*HWp per channel; < 2^26

    float q[CC][PXT];
#pragma unroll
    for (int i = 0; i < CC; i++) {
#pragma unroll
        for (int p = 0; p < PXT; p++) q[i][p] = 0.f;
    }

    // Pass 1: stream `current` channel planes, accumulate pred_i = sum_j CM[i][j]*c_j
#pragma unroll
    for (int j = 0; j < CC; j++) {
        float4 cu = *(const float4*)(current + base + j * HWp);  // 4 px, 16B coalesced
        const float* wrow = &cmT[j * CMS];   // broadcast reads, conflict-free
#pragma unroll
        for (int i = 0; i < CC; i++) {
            float w = wrow[i];
            q[i][0] = fmaf(w, cu.x, q[i][0]);
            q[i][1] = fmaf(w, cu.y, q[i][1]);
            q[i][2] = fmaf(w, cu.z, q[i][2]);
            q[i][3] = fmaf(w, cu.w, q[i][3]);
        }
    }

    // Pass 2: stream `prior`, multiply in, accumulate per-pixel normalizer
    float s[PXT] = {0.f, 0.f, 0.f, 0.f};
#pragma unroll
    for (int i = 0; i < CC; i++) {
        float4 pu = *(const float4*)(prior + base + i * HWp);
        q[i][0] *= pu.x; s[0] += q[i][0];
        q[i][1] *= pu.y; s[1] += q[i][1];
        q[i][2] *= pu.z; s[2] += q[i][2];
        q[i][3] *= pu.w; s[3] += q[i][3];
    }
    float r[PXT];
#pragma unroll
    for (int p = 0; p < PXT; p++) r[p] = 1.f / s[p];

    // Epilogue: out[n*21 + i] fp32; this thread owns 84 contiguous floats = 21 x float4
    // (offset n0*CC*4 = 336*t bytes -> 16B aligned)
    float4* outv = (float4*)(out + (size_t)n0 * CC);
#pragma unroll
    for (int k = 0; k < (PXT * CC) / 4; k++) {
        float4 vv;
        float ev[4];
#pragma unroll
        for (int m = 0; m < 4; m++) {
            int e = 4 * k + m;
            int p = e / CC, i = e - p * CC;
            ev[m] = q[i][p] * r[p];
        }
        vv.x = ev[0]; vv.y = ev[1]; vv.z = ev[2]; vv.w = ev[3];
        outv[k] = vv;
    }
}

extern "C" void kernel_launch(void* const* d_in, const int* in_sizes, int n_in,
                              void* d_out, int out_size, void* d_ws, size_t ws_size,
                              hipStream_t stream) {
    const float* prior   = (const float*)d_in[0];
    const float* current = (const float*)d_in[1];
    const float* cm      = (const float*)d_in[2];
    float* out           = (float*)d_out;

    const int threads = NPIX / PXT;        // 524288
    dim3 grid(threads / 256), block(256);  // 2048 blocks
    ep_kernel<<<grid, block, 0, stream>>>(prior, current, cm, out);
}